// Round 7
// baseline (484.566 us; speedup 1.0000x reference)
//
#include <hip/hip_runtime.h>
#include <hip/hip_bf16.h>
#include <cstdint>

#define NN 50000
#define NE 800000
#define DH 128
#define TILES 50000          // 16-edge tiles
#define NCHUNK 4

typedef __bf16 bf16;
typedef __bf16 bf16x8 __attribute__((ext_vector_type(8)));
typedef float  f32x4  __attribute__((ext_vector_type(4)));

__device__ __forceinline__ float fast_silu(float x) {
    float e = __expf(-x);
    return x * __builtin_amdgcn_rcpf(1.0f + e);
}

// ---------------- k0: weight prep (transpose + bf16) ----------------
__global__ void prep_kernel(const float* __restrict__ W1, const float* __restrict__ W2,
                            const float* __restrict__ W3, const float* __restrict__ b1,
                            const float* __restrict__ g1, const float* __restrict__ bt1,
                            const float* __restrict__ b2, const float* __restrict__ b3,
                            const float* __restrict__ W4,
                            bf16* __restrict__ w1aT, bf16* __restrict__ w1bT,
                            bf16* __restrict__ w2T,  bf16* __restrict__ w3T,
                            float* __restrict__ smalls) {
    int i = blockIdx.x * 256 + threadIdx.x;   // 0..16383
    int n = i >> 7, k = i & 127;
    w1aT[i] = (bf16)W1[k * DH + n];
    w1bT[i] = (bf16)W1[(k + DH) * DH + n];
    w2T[i]  = (bf16)W2[k * DH + n];
    w3T[i]  = (bf16)W3[k * DH + n];
    if (i < DH) {
        smalls[i]          = W1[256 * DH + i]; // w1c
        smalls[DH + i]     = b1[i];
        smalls[2 * DH + i] = g1[i];
        smalls[3 * DH + i] = bt1[i];
        smalls[4 * DH + i] = b2[i];
        smalls[5 * DH + i] = b3[i];
        smalls[6 * DH + i] = W4[i];
    }
}

// ---------------- k1: A = h@W1a, B = h@W1b (bf16 out) ----------------
__global__ __launch_bounds__(256) void node_kernel(const float* __restrict__ h,
                                                   const bf16* __restrict__ w1aT,
                                                   const bf16* __restrict__ w1bT,
                                                   bf16* __restrict__ An,
                                                   bf16* __restrict__ Bn) {
    int lane = threadIdx.x & 63, wid = threadIdx.x >> 6;
    int r = lane & 15, g = lane >> 4;
    int wt = blockIdx.x * 4 + wid;
    if (wt >= (NN / 16)) return;
    int base = wt * 16;
    int node = base + r;

    bf16x8 ha[4];
#pragma unroll
    for (int s = 0; s < 4; s++) {
        const float* hp = h + (size_t)node * DH + s * 32 + g * 8;
        float4 p0 = *(const float4*)hp;
        float4 p1 = *(const float4*)(hp + 4);
        ha[s][0] = (bf16)p0.x; ha[s][1] = (bf16)p0.y;
        ha[s][2] = (bf16)p0.z; ha[s][3] = (bf16)p0.w;
        ha[s][4] = (bf16)p1.x; ha[s][5] = (bf16)p1.y;
        ha[s][6] = (bf16)p1.z; ha[s][7] = (bf16)p1.w;
    }
#pragma unroll
    for (int t = 0; t < 16; t++) {
        const bf16* wmat = (t < 8) ? w1aT : w1bT;
        int n = (t & 7) * 16 + r;
        f32x4 acc = {0.f, 0.f, 0.f, 0.f};
#pragma unroll
        for (int s = 0; s < 4; s++) {
            bf16x8 wb = *(const bf16x8*)(wmat + n * DH + s * 32 + g * 8);
            acc = __builtin_amdgcn_mfma_f32_16x16x32_bf16(ha[s], wb, acc, 0, 0, 0);
        }
        bf16* dst = (t < 8) ? An : Bn;
#pragma unroll
        for (int jj = 0; jj < 4; jj++)
            dst[(size_t)(base + g * 4 + jj) * DH + (t & 7) * 16 + r] = (bf16)acc[jj];
    }
}

// ---------------- k2: out = x ----------------
__global__ void init_kernel(const float* __restrict__ x, float* __restrict__ out, int n) {
    int i = blockIdx.x * 256 + threadIdx.x;
    if (i < n) out[i] = x[i];
}

// ---------------- Phase A: gather + silu + LN -> Z (A-frag layout) ----------------
__global__ __launch_bounds__(256) void edgeA_kernel(
    const bf16* __restrict__ An, const bf16* __restrict__ Bn,
    const float* __restrict__ smalls, const int* __restrict__ e,
    const float* __restrict__ d2, bf16* __restrict__ Z,
    int tile0, int nt) {
    __shared__ float sSm[4 * 128];
    int tid = threadIdx.x;
    if (tid < 128) {
#pragma unroll
        for (int a = 0; a < 4; a++) sSm[a * 128 + tid] = smalls[a * 128 + tid];
    }
    __syncthreads();
    const float* s_w1c = sSm;
    const float* s_b1  = sSm + 128;
    const float* s_g1  = sSm + 256;
    const float* s_bt1 = sSm + 384;

    int lane = tid & 63, wid = tid >> 6;
    int r = lane & 15, g = lane >> 4;
    int wgid = blockIdx.x * 4 + wid;
    int nw = gridDim.x * 4;

    for (int lt = wgid; lt < nt; lt += nw) {
        int base = (tile0 + lt) * 16;
        int ei = e[base + r];
        int ej = e[NE + base + r];
        float d2v = d2[base + r];
        const bf16* Ar = An + (size_t)ei * DH;
        const bf16* Br = Bn + (size_t)ej * DH;

        float z[4][8];
#pragma unroll
        for (int s = 0; s < 4; s++) {
            bf16x8 av = *(const bf16x8*)(Ar + s * 32 + g * 8);
            bf16x8 bv = *(const bf16x8*)(Br + s * 32 + g * 8);
#pragma unroll
            for (int j = 0; j < 8; j++) {
                int f = s * 32 + g * 8 + j;
                float zz = (float)av[j] + (float)bv[j] + d2v * s_w1c[f] + s_b1[f];
                z[s][j] = fast_silu(zz);
            }
        }
        float sum = 0.f, sq = 0.f;
#pragma unroll
        for (int s = 0; s < 4; s++)
#pragma unroll
            for (int j = 0; j < 8; j++) { sum += z[s][j]; sq += z[s][j] * z[s][j]; }
        sum += __shfl_xor(sum, 16); sq += __shfl_xor(sq, 16);
        sum += __shfl_xor(sum, 32); sq += __shfl_xor(sq, 32);
        float mu = sum * 0.0078125f;
        float var = sq * 0.0078125f - mu * mu;
        float rs = __builtin_amdgcn_rsqf(var + 1e-5f);

        bf16* zp = Z + (size_t)lt * 2048 + g * 128 + r * 8;
#pragma unroll
        for (int s = 0; s < 4; s++) {
            bf16x8 af;
#pragma unroll
            for (int j = 0; j < 8; j++) {
                int f = s * 32 + g * 8 + j;
                af[j] = (bf16)((z[s][j] - mu) * rs * s_g1[f] + s_bt1[f]);
            }
            *(bf16x8*)(zp + s * 512) = af;
        }
    }
}

// ---------------- Phase B: cooperative 128-edge tiles ----------------
// 8 waves/block; wave w owns n-stripe [16w,16w+16) for ALL 128 edges.
// W2T/W3T stripe fragments + b2/b3/W4 hoisted in registers (zero weight
// loads in loop). Z staged once to LDS; y exchanged via XOR-swizzled LDS
// tile (byte ^= (edge&7)<<4 kills the row-major-128 16-way conflict).
// LDS 70144 B -> 2 blocks/CU.
__global__ __launch_bounds__(512, 2) void edgeB_kernel(
    const bf16* __restrict__ Z, const bf16* __restrict__ w2T,
    const bf16* __restrict__ w3T, const float* __restrict__ smalls,
    const float* __restrict__ b4p, const int* __restrict__ e,
    const float* __restrict__ dxv, float* __restrict__ out,
    int t1280, int nt128) {
    __shared__ __align__(16) bf16 sZ[128 * 128];
    __shared__ __align__(16) bf16 sY[128 * 128];
    __shared__ float sP[8 * 128];
    __shared__ int sEi[128];

    int tid = threadIdx.x;
    int lane = tid & 63, wid = tid >> 6;      // wid = n-stripe
    int r = lane & 15, g = lane >> 4;

    bf16x8 w2f[4], w3f[4];
    {
        const bf16* w2p = w2T + (16 * wid + r) * 128 + g * 8;
        const bf16* w3p = w3T + (16 * wid + r) * 128 + g * 8;
#pragma unroll
        for (int s = 0; s < 4; s++) {
            w2f[s] = *(const bf16x8*)(w2p + s * 32);
            w3f[s] = *(const bf16x8*)(w3p + s * 32);
        }
    }
    float b2v = smalls[512 + 16 * wid + r];
    float b3v = smalls[640 + 16 * wid + r];
    float w4v = smalls[768 + 16 * wid + r];
    float b4v = b4p[0];

    char* zb = (char*)sZ;
    char* yb = (char*)sY;

    for (int it = blockIdx.x; it < nt128; it += gridDim.x) {
        size_t zbase = (size_t)it * 16384;
        int ebase = (t1280 + it) * 128;

        __syncthreads();                       // prev iter done with sZ/sEi/sP
        {
            bf16x8 t0 = *(const bf16x8*)(Z + zbase + (size_t)(0 * 512 + tid) * 8);
            bf16x8 t1 = *(const bf16x8*)(Z + zbase + (size_t)(1 * 512 + tid) * 8);
            bf16x8 t2 = *(const bf16x8*)(Z + zbase + (size_t)(2 * 512 + tid) * 8);
            bf16x8 t3 = *(const bf16x8*)(Z + zbase + (size_t)(3 * 512 + tid) * 8);
            *(bf16x8*)&sZ[(0 * 512 + tid) * 8] = t0;
            *(bf16x8*)&sZ[(1 * 512 + tid) * 8] = t1;
            *(bf16x8*)&sZ[(2 * 512 + tid) * 8] = t2;
            *(bf16x8*)&sZ[(3 * 512 + tid) * 8] = t3;
            if (tid < 128) sEi[tid] = e[ebase + tid];
        }
        __syncthreads();

        // GEMM1: y[edge][16w+r] = silu(zn @ W2 + b2), y -> swizzled LDS
#pragma unroll
        for (int m = 0; m < 8; m++) {
            f32x4 acc = {0.f, 0.f, 0.f, 0.f};
#pragma unroll
            for (int s = 0; s < 4; s++) {
                bf16x8 za = *(const bf16x8*)(zb + m * 4096 + s * 1024 + g * 256 + r * 16);
                acc = __builtin_amdgcn_mfma_f32_16x16x32_bf16(za, w2f[s], acc, 0, 0, 0);
            }
            int nb = (16 * wid + r) * 2;
#pragma unroll
            for (int jj = 0; jj < 4; jj++) {
                int edge = 16 * m + 4 * g + jj;
                int addr = (edge * 256 + nb) ^ ((edge & 7) << 4);
                *(bf16*)(yb + addr) = (bf16)fast_silu(acc[jj] + b2v);
            }
        }
        __syncthreads();

        // GEMM2: p[edge][16w+r] = y @ W3 ; scale partials -> sP
#pragma unroll
        for (int m = 0; m < 8; m++) {
            f32x4 acc = {0.f, 0.f, 0.f, 0.f};
#pragma unroll
            for (int s = 0; s < 4; s++) {
                int addr = ((16 * m + r) * 256 + s * 64 + g * 16) ^ ((r & 7) << 4);
                bf16x8 ya = *(const bf16x8*)(yb + addr);
                acc = __builtin_amdgcn_mfma_f32_16x16x32_bf16(ya, w3f[s], acc, 0, 0, 0);
            }
#pragma unroll
            for (int jj = 0; jj < 4; jj++) {
                float v = fast_silu(acc[jj] + b3v) * w4v;
                v += __shfl_xor(v, 1);
                v += __shfl_xor(v, 2);
                v += __shfl_xor(v, 4);
                v += __shfl_xor(v, 8);
                if (r == 0) sP[wid * 128 + 16 * m + 4 * g + jj] = v;
            }
        }
        __syncthreads();

        // scale + scatter (3 components x 128 edges)
        if (tid < 384) {
            int eidx = tid & 127, c = tid >> 7;
            float s = sP[eidx] + sP[128 + eidx] + sP[256 + eidx] + sP[384 + eidx]
                    + sP[512 + eidx] + sP[640 + eidx] + sP[768 + eidx] + sP[896 + eidx];
            float scale = s + b4v;
            atomicAdd(&out[(size_t)sEi[eidx] * 3 + c],
                      dxv[(size_t)(ebase + eidx) * 3 + c] * scale);
        }
    }
}

extern "C" void kernel_launch(void* const* d_in, const int* in_sizes, int n_in,
                              void* d_out, int out_size, void* d_ws, size_t ws_size,
                              hipStream_t stream) {
    const float* h   = (const float*)d_in[0];
    const float* x   = (const float*)d_in[1];
    const int*   e   = (const int*)d_in[2];
    const float* dxv = (const float*)d_in[3];
    const float* d2  = (const float*)d_in[4];
    const float* W1  = (const float*)d_in[5];
    const float* b1  = (const float*)d_in[6];
    const float* g1  = (const float*)d_in[7];
    const float* bt1 = (const float*)d_in[8];
    const float* W2  = (const float*)d_in[9];
    const float* b2  = (const float*)d_in[10];
    const float* W3  = (const float*)d_in[11];
    const float* b3  = (const float*)d_in[12];
    const float* W4  = (const float*)d_in[13];
    const float* b4  = (const float*)d_in[14];

    char* ws = (char*)d_ws;
    bf16* An     = (bf16*)(ws);                        // 12,800,000
    bf16* Bn     = (bf16*)(ws + 12800000);             // 12,800,000
    bf16* w1aT   = (bf16*)(ws + 25600000);             // 32768
    bf16* w1bT   = (bf16*)(ws + 25632768);             // 32768
    bf16* w2T    = (bf16*)(ws + 25665536);             // 32768
    bf16* w3T    = (bf16*)(ws + 25698304);             // 32768
    float* smalls = (float*)(ws + 25731072);           // 3584
    bf16* Z      = (bf16*)(ws + 25734656);             // <= 12504*4096 B = 51.2 MB
    float* out   = (float*)d_out;

    prep_kernel<<<64, 256, 0, stream>>>(W1, W2, W3, b1, g1, bt1, b2, b3, W4,
                                        w1aT, w1bT, w2T, w3T, smalls);
    node_kernel<<<(NN / 16 + 3) / 4, 256, 0, stream>>>(h, w1aT, w1bT, An, Bn);
    init_kernel<<<(NN * 3 + 255) / 256, 256, 0, stream>>>(x, out, NN * 3);

    // 6250 128-edge tiles split 1563/1563/1562/1562
    int starts[NCHUNK + 1] = {0, 1563, 3126, 4688, 6250};
    for (int c = 0; c < NCHUNK; ++c) {
        int t1280 = starts[c];
        int nt128 = starts[c + 1] - starts[c];
        edgeA_kernel<<<1024, 256, 0, stream>>>(An, Bn, smalls, e, d2, Z,
                                               t1280 * 8, nt128 * 8);
        edgeB_kernel<<<512, 512, 0, stream>>>(Z, w2T, w3T, smalls, b4,
                                              e, dxv, out, t1280, nt128);
    }
}